// Round 9
// baseline (210.839 us; speedup 1.0000x reference)
//
#include <hip/hip_runtime.h>
#include <hip/hip_bf16.h>
#include <hip/hip_fp16.h>

// EnhancedProxyNCALoss: B=4096, C=10000, D=128, SCALE=10, alpha=.25, gamma=2,
// k = int(9999*0.3) = 2999.
// FUSED pipeline: prep (normalize+bf16 into ws, zero out) -> ONE kernel:
//   block = 16 batch rows x 1024 threads (16 waves), sim NEVER materialized.
//   Phase 1: sweep 10000 proxies in 16-col wave-tiles via MFMA, build per-row
//            1024-bin (10-bit key16 prefix) histograms in LDS (2 rows packed
//            per u32 word: counts < 65536, no carry between halves).
//   Scan:    wave w suffix-scans row w's bins -> boundary bin b, fill, cntb.
//   Phase 2: recompute MFMA tiles (B is L2-resident, recompute < re-read),
//            masked exp-sum: exact exp for bins > b, bin-b sum scaled by
//            fill/cntb (mean-fill; bin spread ~3% -> denom error <0.1%).
// NO float LDS atomics anywhere (they compile to CAS loops - round 7 lesson).

#define BATCH   4096
#define NCLASS  10000
#define EDIM    128
#define KSEL    2999
#define NBIN    1024
#define MLOG    10.0f   // sim <= 10 always (cosine * SCALE) -> safe softmax max

typedef __attribute__((ext_vector_type(8))) short short8;
typedef __attribute__((ext_vector_type(4))) float floatx4;

__device__ __forceinline__ unsigned short f2bf(float f) {
    unsigned int u = __float_as_uint(f);
    unsigned int r = (u + 0x7FFFu + ((u >> 16) & 1u)) >> 16;   // RNE
    return (unsigned short)r;
}
// float -> half (RNE) -> monotonic 16-bit key (order-preserving)
__device__ __forceinline__ unsigned int f2key16(float x) {
    unsigned short hb = __half_as_ushort(__float2half(x));
    return (hb & 0x8000u) ? (unsigned int)(~hb & 0xFFFFu)
                          : (unsigned int)(hb | 0x8000u);
}

// ---------------------------------------------------------------- prep ------
__global__ __launch_bounds__(256) void prep_kernel(
    const float* __restrict__ emb, const float* __restrict__ px,
    unsigned short* __restrict__ px_bf, unsigned short* __restrict__ emb_bf,
    float* __restrict__ out)
{
    const int tid  = threadIdx.x;
    if (blockIdx.x == 0 && tid == 0) out[0] = 0.0f;
    const int lane = tid & 63;
    const int w    = tid >> 6;
    const int row  = blockIdx.x * 4 + w;   // grid = 3524 -> rows 0..14095

    const float* src;
    unsigned short* dst;
    float scale;
    if (row < NCLASS) {
        src = px + (size_t)row * EDIM;  dst = px_bf + (size_t)row * EDIM;  scale = 1.0f;
    } else {
        int r = row - NCLASS;
        src = emb + (size_t)r * EDIM;   dst = emb_bf + (size_t)r * EDIM;   scale = 10.0f;
    }
    float a = src[lane], b = src[lane + 64];
    float ss = a * a + b * b;
    #pragma unroll
    for (int off = 32; off; off >>= 1) ss += __shfl_xor(ss, off);
    float inv = scale / fmaxf(sqrtf(ss), 1e-12f);
    dst[lane]      = f2bf(a * inv);
    dst[lane + 64] = f2bf(b * inv);
}

// --------------------------------------------------------------- fused ------
__global__ __launch_bounds__(1024) void fused_kernel(
    const unsigned short* __restrict__ emb_bf,
    const unsigned short* __restrict__ px_bf,
    const int* __restrict__ labels,
    const float* __restrict__ cw,
    float* __restrict__ out)
{
    __shared__ __align__(16) unsigned int hist[8 * NBIN];  // [pair][bin] 32 KB
    __shared__ float redS[16][16];    // [row][wave]
    __shared__ float redB[16][16];
    __shared__ float s_pos[16];
    __shared__ int   s_lab[16];
    __shared__ unsigned int s_b[16], s_fill[16], s_cntb[16];

    const int tid  = threadIdx.x;
    const int lane = tid & 63;
    const int w    = tid >> 6;        // wave 0..15
    const int fm   = lane & 15;
    const int fq   = lane >> 4;
    const int r0   = blockIdx.x * 16;

    // zero hist (8192 words / 1024 threads = 8 each) + stage labels
    {
        uint4 z = make_uint4(0u, 0u, 0u, 0u);
        *(uint4*)&hist[tid * 8]     = z;
        *(uint4*)&hist[tid * 8 + 4] = z;
    }
    if (tid < 16) s_lab[tid] = labels[r0 + tid];
    __syncthreads();

    // A fragments in registers: lane (fm,fq) holds A[row=fm][k=kk*32+fq*8..+8]
    // (16 rows exactly matches the MFMA A-operand lane->m mapping).
    short8 afrag[4];
    #pragma unroll
    for (int kk = 0; kk < 4; ++kk)
        afrag[kk] = *(const short8*)(emb_bf + (size_t)(r0 + fm) * EDIM + kk * 32 + fq * 8);

    int labR[4];
    #pragma unroll
    for (int r = 0; r < 4; ++r) labR[r] = s_lab[fq * 4 + r];

    // ---- phase 1: MFMA sweep + histogram ----
    // wave w covers cols t*256 + w*16 + fm; 10000 % 16 == 0 -> no lane guards.
    for (int t = 0; t < 40; ++t) {
        int cb = t * 256 + w * 16;
        if (cb >= NCLASS) continue;          // uniform per wave
        const int c = cb + fm;               // c <= 9999 always
        const unsigned short* bp = px_bf + (size_t)c * EDIM;
        short8 bfrag[4];
        #pragma unroll
        for (int kk = 0; kk < 4; ++kk)
            bfrag[kk] = *(const short8*)(bp + kk * 32 + fq * 8);
        floatx4 acc = (floatx4){0.f, 0.f, 0.f, 0.f};
        #pragma unroll
        for (int kk = 0; kk < 4; ++kk)
            acc = __builtin_amdgcn_mfma_f32_16x16x32_bf16(afrag[kk], bfrag[kk], acc, 0, 0, 0);
        // C/D: col(px row) = fm (via B), row(emb) = fq*4 + r
        #pragma unroll
        for (int r = 0; r < 4; ++r) {
            int row = fq * 4 + r;
            if (c != labR[r]) {
                unsigned int bin = f2key16(acc[r]) >> 6;
                atomicAdd(&hist[(row >> 1) * NBIN + bin], (row & 1) ? 65536u : 1u);
            } else {
                s_pos[row] = acc[r];         // exactly one writer per row
            }
        }
    }
    __syncthreads();

    // ---- per-row suffix scan: wave w handles row w ----
    {
        const int row  = w;
        const int pair = row >> 1;
        const int sh   = (row & 1) * 16;
        unsigned int v[16], sfx[16];
        #pragma unroll
        for (int i = 0; i < 16; ++i)
            v[i] = (hist[pair * NBIN + lane * 16 + i] >> sh) & 0xFFFFu;
        sfx[15] = v[15];
        #pragma unroll
        for (int i = 14; i >= 0; --i) sfx[i] = sfx[i + 1] + v[i];
        unsigned int tot = sfx[0], s = tot;
        #pragma unroll
        for (int off = 1; off < 64; off <<= 1) {
            unsigned int o = __shfl_down(s, off);
            if (lane + off < 64) s += o;
        }
        unsigned int above = s - tot;        // counts in strictly-higher lanes
        #pragma unroll
        for (int i = 0; i < 16; ++i) {
            unsigned int cur = sfx[i] + above;
            unsigned int nxt = ((i < 15) ? sfx[i + 1] : 0u) + above;
            if (cur >= KSEL && nxt < KSEL) {  // exactly one (lane,i)
                s_b[row]    = (unsigned int)(lane * 16 + i);
                s_fill[row] = KSEL - nxt;
                s_cntb[row] = v[i];
            }
        }
    }
    __syncthreads();

    // ---- phase 2: recompute MFMA, masked exp-sum ----
    unsigned int bR[4];
    #pragma unroll
    for (int r = 0; r < 4; ++r) bR[r] = s_b[fq * 4 + r];
    float sum[4] = {0.f, 0.f, 0.f, 0.f}, bsum[4] = {0.f, 0.f, 0.f, 0.f};

    for (int t = 0; t < 40; ++t) {
        int cb = t * 256 + w * 16;
        if (cb >= NCLASS) continue;
        const int c = cb + fm;
        const unsigned short* bp = px_bf + (size_t)c * EDIM;
        short8 bfrag[4];
        #pragma unroll
        for (int kk = 0; kk < 4; ++kk)
            bfrag[kk] = *(const short8*)(bp + kk * 32 + fq * 8);
        floatx4 acc = (floatx4){0.f, 0.f, 0.f, 0.f};
        #pragma unroll
        for (int kk = 0; kk < 4; ++kk)
            acc = __builtin_amdgcn_mfma_f32_16x16x32_bf16(afrag[kk], bfrag[kk], acc, 0, 0, 0);
        #pragma unroll
        for (int r = 0; r < 4; ++r) {
            if (c != labR[r]) {
                unsigned int bin = f2key16(acc[r]) >> 6;
                if (bin >= bR[r]) {
                    float e = __expf(acc[r] - MLOG);
                    if (bin > bR[r]) sum[r] += e; else bsum[r] += e;
                }
            }
        }
    }

    // reduce across fm within each fq-group (xor of bits 0..3 keeps fq fixed)
    #pragma unroll
    for (int off = 1; off < 16; off <<= 1) {
        #pragma unroll
        for (int r = 0; r < 4; ++r) {
            sum[r]  += __shfl_xor(sum[r], off);
            bsum[r] += __shfl_xor(bsum[r], off);
        }
    }
    if (fm == 0) {
        #pragma unroll
        for (int r = 0; r < 4; ++r) {
            redS[fq * 4 + r][w] = sum[r];
            redB[fq * 4 + r][w] = bsum[r];
        }
    }
    __syncthreads();

    // ---- per-row focal loss ----
    if (tid < 16) {
        float S = 0.f, Bs = 0.f;
        #pragma unroll
        for (int i = 0; i < 16; ++i) { S += redS[tid][i]; Bs += redB[tid][i]; }
        float ep    = __expf(s_pos[tid] - MLOG);
        float denom = S + Bs * ((float)s_fill[tid] / (float)s_cntb[tid]) + ep;
        float p     = ep / denom;
        float ce    = -logf(p + 1e-8f);
        float focal = 0.25f * (1.0f - p) * (1.0f - p) * ce;
        redS[0][tid] = focal * cw[s_lab[tid]] * (1.0f / (float)BATCH);
    }
    __syncthreads();
    if (tid == 0) {
        float t = 0.f;
        #pragma unroll
        for (int i = 0; i < 16; ++i) t += redS[0][i];
        atomicAdd(out, t);
    }
}

// ------------------------------------------------------------ launcher ------
extern "C" void kernel_launch(void* const* d_in, const int* in_sizes, int n_in,
                              void* d_out, int out_size, void* d_ws, size_t ws_size,
                              hipStream_t stream) {
    const float* emb    = (const float*)d_in[0];   // 4096 x 128
    const int*   labels = (const int*)d_in[1];     // 4096
    const float* cw     = (const float*)d_in[2];   // 10000
    const float* px     = (const float*)d_in[3];   // 10000 x 128
    float* out = (float*)d_out;
    char*  wsc = (char*)d_ws;

    unsigned short* px_bf  = (unsigned short*)wsc;               // 10000*128 bf16
    unsigned short* emb_bf = (unsigned short*)(wsc + 2560000);   // 4096*128 bf16

    prep_kernel<<<3524, 256, 0, stream>>>(emb, px, px_bf, emb_bf, out);
    fused_kernel<<<BATCH / 16, 1024, 0, stream>>>(emb_bf, px_bf, labels, cw, out);
}